// Round 3
// baseline (488.601 us; speedup 1.0000x reference)
//
#include <hip/hip_runtime.h>
#include <hip/hip_bf16.h>
#include <cstdint>
#include <cstddef>

#define N_NODES 262144
#define NGRAPH  2048
#define DIM     512
#define OUTD    128

typedef __attribute__((ext_vector_type(8))) short  short8;
typedef __attribute__((ext_vector_type(4))) float  floatx4;

__device__ inline unsigned short f2bf(float f) {
    union { float f; uint32_t u; } v; v.f = f;
    uint32_t u = v.u;
    return (unsigned short)((u + 0x7fffu + ((u >> 16) & 1u)) >> 16);
}
__device__ inline float bf2f(unsigned short h) {
    union { uint32_t u; float f; } v; v.u = ((uint32_t)h) << 16; return v.f;
}

__device__ __forceinline__ void gload_lds16(const void* g, void* l) {
    __builtin_amdgcn_global_load_lds((const __attribute__((address_space(1))) void*)g,
                                     (__attribute__((address_space(3))) void*)l, 16, 0, 0);
}

__device__ __forceinline__ int seg_lower_bound(const int* __restrict__ seg, int b) {
    int lo = 0, hi = N_NODES;
    while (lo < hi) { int mid = (lo + hi) >> 1; if (seg[mid] < b) lo = mid + 1; else hi = mid; }
    return lo;
}

// ============ K1: init (sum-pool, left_att, x->bf16) + all weight prep ============
// blocks [0,2048): per-graph init | [2048,4096): Wcomb rows | [4096,4352): WnT transpose
template<bool WRITE_XBF>
__global__ __launch_bounds__(256) void k_init(const float* __restrict__ x,
        const int* __restrict__ seg, const float* __restrict__ watl,
        const float* __restrict__ Wih, const float* __restrict__ Whh,
        const float* __restrict__ Wnode,
        float* __restrict__ left_att, float* __restrict__ hcur,
        unsigned short* __restrict__ hcur_bf, unsigned short* __restrict__ xbf,
        unsigned short* __restrict__ Wcomb, unsigned short* __restrict__ WnT) {
    int t = threadIdx.x;
    int bid = blockIdx.x;

    if (bid >= 4096) {            // ---- WnT transpose (256 blocks) ----
        __shared__ float tile[32][33];
        int idx = bid - 4096;
        int bx = idx >> 4, by = idx & 15;
        int tx = t & 31, ty = t >> 5;
        for (int r = 0; r < 32; r += 8)
            tile[ty + r][tx] = Wnode[(size_t)(bx * 32 + ty + r) * DIM + by * 32 + tx];
        __syncthreads();
        for (int r = 0; r < 32; r += 8)
            WnT[(size_t)(by * 32 + ty + r) * DIM + bx * 32 + tx] = f2bf(tile[tx][ty + r]);
        return;
    }
    if (bid >= 2048) {            // ---- Wcomb row build (2048 blocks) ----
        int c = bid - 2048;
        int h = c >> 2, role = c & 3;
        int k = t * 4;
        float4 src = make_float4(0.f, 0.f, 0.f, 0.f);
        if (role == 0) {
            src = (k < 512) ? *reinterpret_cast<const float4*>(Wih + (size_t)h * DIM + k)
                            : *reinterpret_cast<const float4*>(Whh + (size_t)h * DIM + (k - 512));
        } else if (role == 1) {
            src = (k < 512) ? *reinterpret_cast<const float4*>(Wih + (size_t)(512 + h) * DIM + k)
                            : *reinterpret_cast<const float4*>(Whh + (size_t)(512 + h) * DIM + (k - 512));
        } else if (role == 2) {
            if (k < 512) src = *reinterpret_cast<const float4*>(Wih + (size_t)(1024 + h) * DIM + k);
        } else {
            if (k >= 512) src = *reinterpret_cast<const float4*>(Whh + (size_t)(1024 + h) * DIM + (k - 512));
        }
        ushort4 o;
        o.x = f2bf(src.x); o.y = f2bf(src.y); o.z = f2bf(src.z); o.w = f2bf(src.w);
        *reinterpret_cast<ushort4*>(Wcomb + (size_t)c * 1024 + k) = o;
        return;
    }

    // ---- per-graph init ----
    __shared__ float wl[DIM];
    __shared__ float red[4 * DIM];
    int b = bid;
    wl[t] = watl[t]; wl[t + 256] = watl[t + 256];
    int s = seg_lower_bound(seg, b);
    int e = seg_lower_bound(seg, b + 1);
    __syncthreads();
    int w = t >> 6, lane = t & 63;
    int f0 = lane * 4;
    float acc[8] = {0.f,0.f,0.f,0.f,0.f,0.f,0.f,0.f};

    auto body = [&](int i) {
        float4 v0 = *reinterpret_cast<const float4*>(x + (size_t)i * DIM + f0);
        float4 v1 = *reinterpret_cast<const float4*>(x + (size_t)i * DIM + 256 + f0);
        acc[0] += v0.x; acc[1] += v0.y; acc[2] += v0.z; acc[3] += v0.w;
        acc[4] += v1.x; acc[5] += v1.y; acc[6] += v1.z; acc[7] += v1.w;
        float dot = v0.x*wl[f0] + v0.y*wl[f0+1] + v0.z*wl[f0+2] + v0.w*wl[f0+3]
                  + v1.x*wl[256+f0] + v1.y*wl[256+f0+1] + v1.z*wl[256+f0+2] + v1.w*wl[256+f0+3];
        #pragma unroll
        for (int off = 32; off > 0; off >>= 1) dot += __shfl_xor(dot, off);
        if (lane == 0) left_att[i] = dot;
        if constexpr (WRITE_XBF) {
            ushort4 o0, o1;
            o0.x = f2bf(v0.x); o0.y = f2bf(v0.y); o0.z = f2bf(v0.z); o0.w = f2bf(v0.w);
            o1.x = f2bf(v1.x); o1.y = f2bf(v1.y); o1.z = f2bf(v1.z); o1.w = f2bf(v1.w);
            *reinterpret_cast<ushort4*>(xbf + (size_t)i * DIM + f0) = o0;
            *reinterpret_cast<ushort4*>(xbf + (size_t)i * DIM + 256 + f0) = o1;
        }
    };
    int i = s + w;
    for (; i + 4 < e; i += 8) { body(i); body(i + 4); }
    if (i < e) body(i);

    #pragma unroll
    for (int j = 0; j < 4; j++) {
        red[w * DIM + f0 + j]       = acc[j];
        red[w * DIM + 256 + f0 + j] = acc[4 + j];
    }
    __syncthreads();
    float s0 = red[t]       + red[DIM + t]       + red[2*DIM + t]       + red[3*DIM + t];
    float s1 = red[256 + t] + red[DIM + 256 + t] + red[2*DIM + 256 + t] + red[3*DIM + 256 + t];
    hcur[(size_t)b * DIM + t] = s0;
    hcur[(size_t)b * DIM + 256 + t] = s1;
    hcur_bf[(size_t)b * DIM + t] = f2bf(s0);
    hcur_bf[(size_t)b * DIM + 256 + t] = f2bf(s1);
}

// ============ K2: fused attention (right-att dot + softmax + weighted sum) ============
// single pass, unsubtracted fp32 exp (|alpha| <~ 30, safe), unroll x2
template<bool XBF>
__global__ __launch_bounds__(256) void k_att(const float* __restrict__ x,
        const unsigned short* __restrict__ xbf, const float* __restrict__ left,
        const int* __restrict__ seg, const float* __restrict__ hcur,
        const float* __restrict__ watr, unsigned short* __restrict__ swbf) {
    __shared__ float red[4 * DIM];
    __shared__ float rsh[4];
    __shared__ float rscal[4];
    int b = blockIdx.x, t = threadIdx.x;
    int w = t >> 6, lane = t & 63;

    // right_att = dot(hcur[b], watr) via wave shfl + cross-wave LDS
    float p = hcur[(size_t)b * DIM + t] * watr[t] + hcur[(size_t)b * DIM + 256 + t] * watr[256 + t];
    #pragma unroll
    for (int off = 32; off > 0; off >>= 1) p += __shfl_xor(p, off);
    if (lane == 0) rsh[w] = p;
    int s = seg_lower_bound(seg, b);
    int e = seg_lower_bound(seg, b + 1);
    __syncthreads();
    float ra = rsh[0] + rsh[1] + rsh[2] + rsh[3];

    float acc[8] = {0.f,0.f,0.f,0.f,0.f,0.f,0.f,0.f};
    float esum = 0.f;
    if constexpr (XBF) {
        int f0 = lane * 8;
        const unsigned short* xb = xbf + f0;
        int i = s + w;
        for (; i + 4 < e; i += 8) {
            float a0 = left[i] + ra;     a0 = a0 >= 0.f ? a0 : 0.01f * a0;
            float a1 = left[i + 4] + ra; a1 = a1 >= 0.f ? a1 : 0.01f * a1;
            short8 v0 = *reinterpret_cast<const short8*>(xb + (size_t)i * DIM);
            short8 v1 = *reinterpret_cast<const short8*>(xb + (size_t)(i + 4) * DIM);
            float e0 = __expf(a0), e1 = __expf(a1);
            esum += e0 + e1;
            #pragma unroll
            for (int j = 0; j < 8; j++)
                acc[j] += e0 * bf2f((unsigned short)v0[j]) + e1 * bf2f((unsigned short)v1[j]);
        }
        if (i < e) {
            float a0 = left[i] + ra; a0 = a0 >= 0.f ? a0 : 0.01f * a0;
            short8 v0 = *reinterpret_cast<const short8*>(xb + (size_t)i * DIM);
            float e0 = __expf(a0);
            esum += e0;
            #pragma unroll
            for (int j = 0; j < 8; j++) acc[j] += e0 * bf2f((unsigned short)v0[j]);
        }
        #pragma unroll
        for (int j = 0; j < 8; j++) red[w * DIM + f0 + j] = acc[j];
    } else {
        int f0 = lane * 4;
        int i = s + w;
        for (; i < e; i += 4) {
            float a0 = left[i] + ra; a0 = a0 >= 0.f ? a0 : 0.01f * a0;
            float e0 = __expf(a0);
            esum += e0;
            float4 v0 = *reinterpret_cast<const float4*>(x + (size_t)i * DIM + f0);
            float4 v1 = *reinterpret_cast<const float4*>(x + (size_t)i * DIM + 256 + f0);
            acc[0] += e0 * v0.x; acc[1] += e0 * v0.y; acc[2] += e0 * v0.z; acc[3] += e0 * v0.w;
            acc[4] += e0 * v1.x; acc[5] += e0 * v1.y; acc[6] += e0 * v1.z; acc[7] += e0 * v1.w;
        }
        #pragma unroll
        for (int j = 0; j < 4; j++) {
            red[w * DIM + f0 + j]       = acc[j];
            red[w * DIM + 256 + f0 + j] = acc[4 + j];
        }
    }
    #pragma unroll
    for (int off = 32; off > 0; off >>= 1) esum += __shfl_xor(esum, off);
    if (lane == 0) rscal[w] = esum;
    __syncthreads();
    float tot = rscal[0] + rscal[1] + rscal[2] + rscal[3];
    float inv = tot > 0.f ? 1.0f / tot : 0.0f;
    float s0 = (red[t]       + red[DIM + t]       + red[2*DIM + t]       + red[3*DIM + t])       * inv;
    float s1 = (red[256 + t] + red[DIM + 256 + t] + red[2*DIM + 256 + t] + red[3*DIM + 256 + t]) * inv;
    swbf[(size_t)b * DIM + t] = f2bf(s0);
    swbf[(size_t)b * DIM + 256 + t] = f2bf(s1);
}

// ============ K3: hg = elu(sw @ WnT^T) -> bf16, 128x128 tile, K=512 ============
__global__ __launch_bounds__(256, 2) void k_gemm1(const unsigned short* __restrict__ A,
        const unsigned short* __restrict__ Wt, unsigned short* __restrict__ Cbf) {
    __shared__ __align__(16) unsigned short lA[2][128 * 64];
    __shared__ __align__(16) unsigned short lW[2][128 * 64];
    int t = threadIdx.x;
    int w = t >> 6, lane = t & 63;
    int wr = w >> 1, wc = w & 1;
    int mbase = blockIdx.x * 128;
    int nbase = blockIdx.y * 128;
    int fr = lane & 15, hi4 = lane >> 4;
    int swz_r = (fr & 7) << 4;
    int rbase = t >> 3;
    int cole = ((((t & 7) * 16) ^ ((rbase & 7) << 4)) >> 1);
    int ldsoff = t * 16;

    floatx4 acc[4][4];
    #pragma unroll
    for (int m = 0; m < 4; m++)
        #pragma unroll
        for (int n = 0; n < 4; n++) {
            acc[m][n][0] = 0.f; acc[m][n][1] = 0.f; acc[m][n][2] = 0.f; acc[m][n][3] = 0.f;
        }

    const unsigned short* gA = A  + (size_t)(mbase + rbase) * DIM + cole;
    const unsigned short* gW = Wt + (size_t)(nbase + rbase) * DIM + cole;
    auto stage = [&](int kk, int buf) {
        #pragma unroll
        for (int c = 0; c < 4; ++c) {
            gload_lds16(gA + (size_t)(c * 32) * DIM + kk, (char*)&lA[buf][0] + c * 4096 + ldsoff);
            gload_lds16(gW + (size_t)(c * 32) * DIM + kk, (char*)&lW[buf][0] + c * 4096 + ldsoff);
        }
    };
    stage(0, 0);
    __syncthreads();
    int cur = 0;
    for (int it = 0; it < 8; ++it) {
        if (it < 7) stage((it + 1) * 64, cur ^ 1);
        #pragma unroll
        for (int ks = 0; ks < 2; ++ks) {
            short8 af[4], bf[4];
            int bc = (ks * 64 + hi4 * 16) ^ swz_r;
            #pragma unroll
            for (int m = 0; m < 4; ++m)
                af[m] = *reinterpret_cast<const short8*>(&lA[cur][((wr*64 + m*16 + fr) * 128 + bc) >> 1]);
            #pragma unroll
            for (int n = 0; n < 4; ++n)
                bf[n] = *reinterpret_cast<const short8*>(&lW[cur][((wc*64 + n*16 + fr) * 128 + bc) >> 1]);
            #pragma unroll
            for (int m = 0; m < 4; ++m)
                #pragma unroll
                for (int n = 0; n < 4; ++n)
                    acc[m][n] = __builtin_amdgcn_mfma_f32_16x16x32_bf16(af[m], bf[n], acc[m][n], 0, 0, 0);
        }
        if (it < 7) __syncthreads();
        cur ^= 1;
    }
    int rq = hi4 * 4;
    #pragma unroll
    for (int m = 0; m < 4; m++)
        #pragma unroll
        for (int n = 0; n < 4; n++) {
            int col = nbase + wc * 64 + n * 16 + fr;
            #pragma unroll
            for (int r = 0; r < 4; r++) {
                int row = mbase + wr * 64 + m * 16 + rq + r;
                float v = acc[m][n][r];
                v = v > 0.f ? v : (__expf(v) - 1.0f);
                Cbf[(size_t)row * DIM + col] = f2bf(v);
            }
        }
}

// ============ K4: fused GRU GEMM + gates: C = [hg|hprev] @ Wcomb^T, K=1024 ============
// Wcomb col c = 4*h + role: role0 = r-sum, role1 = z-sum, role2 = gi_n, role3 = gh_n
__global__ __launch_bounds__(256, 2) void k_gemmgate(const unsigned short* __restrict__ Ah,
        const unsigned short* __restrict__ Ac, const unsigned short* __restrict__ Wc,
        const float* __restrict__ bih, const float* __restrict__ bhh,
        float* __restrict__ hcur, unsigned short* __restrict__ houtbf) {
    __shared__ __align__(16) unsigned short lA[2][128 * 64];
    __shared__ __align__(16) unsigned short lW[2][128 * 64];
    int t = threadIdx.x;
    int w = t >> 6, lane = t & 63;
    int wr = w >> 1, wc = w & 1;
    int mbase = blockIdx.x * 128;
    int nbase = blockIdx.y * 128;
    int fr = lane & 15, hi4 = lane >> 4;
    int swz_r = (fr & 7) << 4;
    int rbase = t >> 3;
    int cole = ((((t & 7) * 16) ^ ((rbase & 7) << 4)) >> 1);
    int ldsoff = t * 16;

    floatx4 acc[4][4];
    #pragma unroll
    for (int m = 0; m < 4; m++)
        #pragma unroll
        for (int n = 0; n < 4; n++) {
            acc[m][n][0] = 0.f; acc[m][n][1] = 0.f; acc[m][n][2] = 0.f; acc[m][n][3] = 0.f;
        }

    auto stage = [&](int it, int buf) {
        int kk = it * 64;
        const unsigned short* Abase = (kk < 512) ? Ah : Ac;
        int kl = (kk < 512) ? kk : kk - 512;
        #pragma unroll
        for (int c = 0; c < 4; ++c) {
            gload_lds16(Abase + (size_t)(mbase + c * 32 + rbase) * 512 + kl + cole,
                        (char*)&lA[buf][0] + c * 4096 + ldsoff);
            gload_lds16(Wc + (size_t)(nbase + c * 32 + rbase) * 1024 + kk + cole,
                        (char*)&lW[buf][0] + c * 4096 + ldsoff);
        }
    };
    stage(0, 0);
    __syncthreads();
    int cur = 0;
    for (int it = 0; it < 16; ++it) {
        if (it < 15) stage(it + 1, cur ^ 1);
        #pragma unroll
        for (int ks = 0; ks < 2; ++ks) {
            short8 af[4], bf[4];
            int bc = (ks * 64 + hi4 * 16) ^ swz_r;
            #pragma unroll
            for (int m = 0; m < 4; ++m)
                af[m] = *reinterpret_cast<const short8*>(&lA[cur][((wr*64 + m*16 + fr) * 128 + bc) >> 1]);
            #pragma unroll
            for (int n = 0; n < 4; ++n)
                bf[n] = *reinterpret_cast<const short8*>(&lW[cur][((wc*64 + n*16 + fr) * 128 + bc) >> 1]);
            #pragma unroll
            for (int m = 0; m < 4; ++m)
                #pragma unroll
                for (int n = 0; n < 4; ++n)
                    acc[m][n] = __builtin_amdgcn_mfma_f32_16x16x32_bf16(af[m], bf[n], acc[m][n], 0, 0, 0);
        }
        if (it < 15) __syncthreads();
        cur ^= 1;
    }

    int role = fr & 3;
    int rq = hi4 * 4;
    #pragma unroll
    for (int m = 0; m < 4; m++) {
        #pragma unroll
        for (int n = 0; n < 4; n++) {
            int col = nbase + wc * 64 + n * 16 + fr;
            int h = col >> 2;
            float br  = bih[h]        + bhh[h];
            float bz  = bih[512 + h]  + bhh[512 + h];
            float bni = bih[1024 + h];
            float bnh = bhh[1024 + h];
            #pragma unroll
            for (int r = 0; r < 4; r++) {
                int row = mbase + wr * 64 + m * 16 + rq + r;
                float v  = acc[m][n][r];
                float x1 = __shfl_xor(v, 1);
                float x2 = __shfl_xor(v, 2);
                float x3 = __shfl_xor(v, 3);
                float rs  = role==0 ? v  : role==1 ? x1 : role==2 ? x2 : x3;
                float zs  = role==1 ? v  : role==0 ? x1 : role==3 ? x2 : x3;
                float gin = role==2 ? v  : role==3 ? x1 : role==0 ? x2 : x3;
                float ghn = role==3 ? v  : role==2 ? x1 : role==1 ? x2 : x3;
                float rg = 1.0f / (1.0f + __expf(-(rs + br)));
                float zg = 1.0f / (1.0f + __expf(-(zs + bz)));
                float nn = tanhf(gin + bni + rg * (ghn + bnh));
                float hp = hcur[(size_t)row * DIM + h];
                float hn = (1.0f - zg) * nn + zg * hp;
                float o  = hn / (1.0f + __expf(-hn));
                if (role == 0) {
                    hcur[(size_t)row * DIM + h] = o;
                    houtbf[(size_t)row * DIM + h] = f2bf(o);
                }
            }
        }
    }
}

// ============ K5: final linear ============
__global__ __launch_bounds__(128) void k_fin(const float* __restrict__ hcur,
        const float* __restrict__ Wlin, const float* __restrict__ blin,
        float* __restrict__ out) {
    __shared__ float rows[16 * DIM];
    int t = threadIdx.x;
    int b0 = blockIdx.x * 16;
    for (int i = t; i < 16 * DIM / 4; i += 128)
        reinterpret_cast<float4*>(rows)[i] = reinterpret_cast<const float4*>(hcur + (size_t)b0 * DIM)[i];
    __syncthreads();
    float acc[16];
    #pragma unroll
    for (int r = 0; r < 16; r++) acc[r] = 0.f;
    #pragma unroll 4
    for (int k = 0; k < DIM; k++) {
        float wv = Wlin[k * OUTD + t];
        #pragma unroll
        for (int r = 0; r < 16; r++) acc[r] += rows[r * DIM + k] * wv;
    }
    float bl = blin[t];
    #pragma unroll
    for (int r = 0; r < 16; r++) out[(size_t)(b0 + r) * OUTD + t] = acc[r] + bl;
}

extern "C" void kernel_launch(void* const* d_in, const int* in_sizes, int n_in,
                              void* d_out, int out_size, void* d_ws, size_t ws_size,
                              hipStream_t stream) {
    const float* x     = (const float*)d_in[0];
    const int*   seg   = (const int*)d_in[1];
    const float* watl  = (const float*)d_in[2];
    const float* watr  = (const float*)d_in[3];
    const float* Wnode = (const float*)d_in[4];
    const float* Wih   = (const float*)d_in[5];
    const float* Whh   = (const float*)d_in[6];
    const float* bih   = (const float*)d_in[7];
    const float* bhh   = (const float*)d_in[8];
    const float* Wlin  = (const float*)d_in[9];
    const float* blin  = (const float*)d_in[10];
    float* out = (float*)d_out;

    char* ws = (char*)d_ws;
    size_t off = 0;
    auto alloc = [&](size_t bytes) -> void* {
        void* p = ws + off;
        off += bytes;
        off = (off + 255) & ~(size_t)255;
        return p;
    };
    float*          left    = (float*)          alloc((size_t)N_NODES * sizeof(float));
    float*          hcur    = (float*)          alloc((size_t)NGRAPH * DIM * sizeof(float));
    unsigned short* hcurbf  = (unsigned short*) alloc((size_t)NGRAPH * DIM * 2);
    unsigned short* hnewbf  = (unsigned short*) alloc((size_t)NGRAPH * DIM * 2);
    unsigned short* hgbf    = (unsigned short*) alloc((size_t)NGRAPH * DIM * 2);
    unsigned short* swbf    = (unsigned short*) alloc((size_t)NGRAPH * DIM * 2);
    unsigned short* WnT     = (unsigned short*) alloc((size_t)DIM * DIM * 2);
    unsigned short* Wcomb   = (unsigned short*) alloc((size_t)2048 * 1024 * 2);
    unsigned short* xbf     = (unsigned short*)(ws + off);
    bool use_xbf = (off + (size_t)N_NODES * DIM * 2) <= ws_size;

    if (use_xbf)
        k_init<true ><<<4352, 256, 0, stream>>>(x, seg, watl, Wih, Whh, Wnode,
                                                left, hcur, hcurbf, xbf, Wcomb, WnT);
    else
        k_init<false><<<4352, 256, 0, stream>>>(x, seg, watl, Wih, Whh, Wnode,
                                                left, hcur, hcurbf, nullptr, Wcomb, WnT);

    for (int ts = 0; ts < 2; ts++) {
        if (use_xbf)
            k_att<true ><<<NGRAPH, 256, 0, stream>>>(x, xbf, left, seg, hcur, watr, swbf);
        else
            k_att<false><<<NGRAPH, 256, 0, stream>>>(x, xbf, left, seg, hcur, watr, swbf);
        k_gemm1<<<dim3(NGRAPH / 128, DIM / 128), 256, 0, stream>>>(swbf, WnT, hgbf);
        // ping-pong bf16 h buffers to avoid write-while-staged race
        const unsigned short* Ac = (ts == 0) ? hcurbf : hnewbf;
        unsigned short*       Ho = (ts == 0) ? hnewbf : hcurbf;
        k_gemmgate<<<dim3(NGRAPH / 128, 2048 / 128), 256, 0, stream>>>(
            hgbf, Ac, Wcomb, bih, bhh, hcur, Ho);
    }
    k_fin<<<NGRAPH / 16, 128, 0, stream>>>(hcur, Wlin, blin, out);
}